// Round 13
// baseline (123.172 us; speedup 1.0000x reference)
//
#include <hip/hip_runtime.h>

// Int8 fake-quant linear (exact integer accumulation):
//   sx = max|x|/128; qx = clamp(rint(x/sx),-128,127)
//   sw = max|w|/127; qw = clamp(rint(w/sw),-127,127)
//   out = mul * (sx*sw*(qx @ qw^T) + bias)
//
// qx/qw stored PERMUTED in workspace, in LDS chunk-plane order (256-row blocks):
//   v4i index = ((blk*32 + kt)*4 + c)*256 + r
// -> GEMM staging is a linear contiguous copy (global_load_lds, lane-linear dest)
// -> fragment reads are 32-lane-contiguous (verified: 0 bank conflicts R3/R5)

typedef int v4i  __attribute__((ext_vector_type(4)));
typedef int v16i __attribute__((ext_vector_type(16)));

#define MDIM 4096
#define NDIM 8192
#define KDIM 2048
#define NT   (KDIM / 64)   // 32 K-tiles of BK=64 int8

typedef __attribute__((address_space(1))) void* gas_ptr;   // global
typedef __attribute__((address_space(3))) void* las_ptr;   // LDS

#define XBLK 1024   // blocks for x; w gets 2048 (total 3072)

// ---------------- absmax: per-block partial maxima (plain stores) ----------------
__global__ __launch_bounds__(256) void absmax2(const float4* __restrict__ x,
                                               const float4* __restrict__ w,
                                               float* __restrict__ partial) {
    const int tid = threadIdx.x;
    const bool isx = blockIdx.x < XBLK;
    float m0 = 0.0f, m1 = 0.0f;
    if (isx) {
        const size_t base = (size_t)blockIdx.x * 256 + tid;       // stride 262144
#pragma unroll
        for (int j = 0; j < 8; j += 2) {
            float4 v0 = x[base + (size_t)j * 262144];
            float4 v1 = x[base + (size_t)(j + 1) * 262144];
            m0 = fmaxf(m0, fmaxf(fmaxf(fabsf(v0.x), fabsf(v0.y)),
                                 fmaxf(fabsf(v0.z), fabsf(v0.w))));
            m1 = fmaxf(m1, fmaxf(fmaxf(fabsf(v1.x), fabsf(v1.y)),
                                 fmaxf(fabsf(v1.z), fabsf(v1.w))));
        }
    } else {
        const size_t base = (size_t)(blockIdx.x - XBLK) * 256 + tid;  // stride 524288
#pragma unroll
        for (int j = 0; j < 8; j += 2) {
            float4 v0 = w[base + (size_t)j * 524288];
            float4 v1 = w[base + (size_t)(j + 1) * 524288];
            m0 = fmaxf(m0, fmaxf(fmaxf(fabsf(v0.x), fabsf(v0.y)),
                                 fmaxf(fabsf(v0.z), fabsf(v0.w))));
            m1 = fmaxf(m1, fmaxf(fmaxf(fabsf(v1.x), fabsf(v1.y)),
                                 fmaxf(fabsf(v1.z), fabsf(v1.w))));
        }
    }
    float m = fmaxf(m0, m1);
#pragma unroll
    for (int off = 32; off > 0; off >>= 1)
        m = fmaxf(m, __shfl_xor(m, off, 64));
    __shared__ float wm[4];
    if ((tid & 63) == 0) wm[tid >> 6] = m;
    __syncthreads();
    if (tid == 0)
        partial[blockIdx.x] = fmaxf(fmaxf(wm[0], wm[1]), fmaxf(wm[2], wm[3]));
}

// ---------------- quantize: reduce partials, then permuted int8 write ----------
__global__ __launch_bounds__(256) void quant2(const float4* __restrict__ x,
                                              v4i* __restrict__ qxp,
                                              const float4* __restrict__ w,
                                              v4i* __restrict__ qwp,
                                              const float* __restrict__ partial,
                                              unsigned* __restrict__ scales) {
    const int tid = threadIdx.x;
    float gx = 0.0f, gw = 0.0f;
#pragma unroll
    for (int j = 0; j < 4; ++j) gx = fmaxf(gx, partial[tid + j * 256]);
#pragma unroll
    for (int j = 0; j < 8; ++j) gw = fmaxf(gw, partial[XBLK + tid + j * 256]);
#pragma unroll
    for (int off = 32; off > 0; off >>= 1) {
        gx = fmaxf(gx, __shfl_xor(gx, off, 64));
        gw = fmaxf(gw, __shfl_xor(gw, off, 64));
    }
    __shared__ float smx[4], smw[4];
    if ((tid & 63) == 0) { smx[tid >> 6] = gx; smw[tid >> 6] = gw; }
    __syncthreads();
    const float fmx = fmaxf(fmaxf(smx[0], smx[1]), fmaxf(smx[2], smx[3]));
    const float fmw = fmaxf(fmaxf(smw[0], smw[1]), fmaxf(smw[2], smw[3]));
    if (blockIdx.x == 0 && tid == 0) {
        scales[0] = __float_as_uint(fmx);
        scales[1] = __float_as_uint(fmw);
    }
    const float sxs = fmx / 128.0f;   // IEEE, matches reference scale
    const float sws = fmw / 127.0f;

    const bool isx = blockIdx.x < XBLK;
    const float4* in = isx ? x : w;
    v4i* outp = isx ? qxp : qwp;
    const int total = isx ? (MDIM * KDIM / 16) : (NDIM * KDIM / 16);
    const int nb = isx ? XBLK : (3072 - XBLK);
    const int b  = isx ? blockIdx.x : (blockIdx.x - XBLK);
    const float s  = isx ? sxs : sws;
    const float lo = isx ? -128.0f : -127.0f;
    for (int idx = b * 256 + tid; idx < total; idx += nb * 256) {
        const int c   = idx & 3;
        const int r   = (idx >> 2) & 255;
        const int kt  = (idx >> 10) & 31;
        const int blk = idx >> 15;
        const float4* src = in + (size_t)(blk * 256 + r) * (KDIM / 4) + kt * 16 + c * 4;
        int q[4];
#pragma unroll
        for (int j = 0; j < 4; ++j) {
            float4 v = src[j];
            int b0 = (int)fminf(fmaxf(rintf(v.x / s), lo), 127.0f);
            int b1 = (int)fminf(fmaxf(rintf(v.y / s), lo), 127.0f);
            int b2 = (int)fminf(fmaxf(rintf(v.z / s), lo), 127.0f);
            int b3 = (int)fminf(fmaxf(rintf(v.w / s), lo), 127.0f);
            q[j] = (b0 & 255) | ((b1 & 255) << 8) | ((b2 & 255) << 16) | (b3 << 24);
        }
        v4i qq; qq[0] = q[0]; qq[1] = q[1]; qq[2] = q[2]; qq[3] = q[3];
        outp[((size_t)(blk * 32 + kt) * 4 + c) * 256 + r] = qq;
    }
}

// ---------------- int8 MFMA GEMM: frag-prefetch pipeline + supertile swizzle ----
// 256x256 tile, ring-4, 8 waves (2M x 4N); wave output 128x64 = 4x2 mfma.
// PIPELINE (AITER-shape, no drains): per tile kt:
//   { stage(kt+3); READ12(tile kt+1 -> other frag set); MFMA16(tile kt);
//     vmcnt(4|0); s_barrier }
// MFMA16 consumes frags read LAST tile -> compiler emits lgkmcnt(12), letting
// the 12 new ds_reads flow in the LDS pipe under the 16 MFMAs. Hazards:
// stage(kt+3) overwrites buf(kt-1) whose reads were consumed before the
// previous barrier; READ12(kt+1) is resident via vmcnt(4)+barrier. No
// lgkmcnt(0), no sched_barrier, one barrier/tile (R4/R6/R8/R11 post-mortems).
__global__ __launch_bounds__(512, 2) void gemm_i8(
    const signed char* __restrict__ qxp, const signed char* __restrict__ qwp,
    const float* __restrict__ bias, const float* __restrict__ mulv,
    const unsigned* __restrict__ scales, float* __restrict__ out) {
    __shared__ signed char ldsA[4][16384];
    __shared__ signed char ldsB[4][16384];

    const int t    = threadIdx.x;
    const int lane = t & 63;
    const int ln   = lane & 31;
    const int hi   = lane >> 5;
    const int w    = t >> 6;      // 0..7
    const int wr   = w >> 2;      // 0..1  (M half)
    const int wc   = w & 3;       // 0..3  (N quarter)

    // 8x8 supertile per XCD (R12 win: FETCH 135->49 MB). Bijective on 16x32.
    const int orig = blockIdx.x;
    const int xcd  = orig & 7;
    const int idx  = orig >> 3;            // 0..63 within the supertile
    const int bm   = (xcd & 1) * 8 + (idx >> 3);   // 0..15
    const int bn   = (xcd >> 1) * 8 + (idx & 7);   // 0..31

    const signed char* srcA = qxp + (size_t)bm * (32 * 16384);
    const signed char* srcB = qwp + (size_t)bn * (32 * 16384);
    signed char* dA = &ldsA[0][0] + t * 16;   // wave-uniform base + lane*16
    signed char* dB = &ldsB[0][0] + t * 16;

    auto stage = [&](int kt) {
        if (kt >= NT) return;
        const int buf = kt & 3;
        const signed char* sa = srcA + kt * 16384 + t * 16;
        const signed char* sb = srcB + kt * 16384 + t * 16;
        __builtin_amdgcn_global_load_lds((gas_ptr)sa,          (las_ptr)(dA + buf * 16384),        16, 0, 0);
        __builtin_amdgcn_global_load_lds((gas_ptr)(sa + 8192), (las_ptr)(dA + buf * 16384 + 8192), 16, 0, 0);
        __builtin_amdgcn_global_load_lds((gas_ptr)sb,          (las_ptr)(dB + buf * 16384),        16, 0, 0);
        __builtin_amdgcn_global_load_lds((gas_ptr)(sb + 8192), (las_ptr)(dB + buf * 16384 + 8192), 16, 0, 0);
    };

    // fragment offsets (chunk-plane: plane = 2*ks+hi, 32-lane contiguous)
    const int aOff = (wr * 128 + ln) * 16;   // + mt*512 + plane*4096
    const int bOff = (wc * 64  + ln) * 16;   // + nt*512 + plane*4096

#define READ12(A0, B0, A1, B1, KT) do {                                       \
        const signed char* _Ab = &ldsA[(KT) & 3][0];                          \
        const signed char* _Bb = &ldsB[(KT) & 3][0];                          \
        const signed char* _A0 = _Ab + hi * 4096 + aOff;                      \
        const signed char* _B0 = _Bb + hi * 4096 + bOff;                      \
        const signed char* _A1 = _Ab + (2 + hi) * 4096 + aOff;                \
        const signed char* _B1 = _Bb + (2 + hi) * 4096 + bOff;                \
        A0[0] = *(const v4i*)(_A0);        A0[1] = *(const v4i*)(_A0 + 512);  \
        A0[2] = *(const v4i*)(_A0 + 1024); A0[3] = *(const v4i*)(_A0 + 1536); \
        B0[0] = *(const v4i*)(_B0);        B0[1] = *(const v4i*)(_B0 + 512);  \
        A1[0] = *(const v4i*)(_A1);        A1[1] = *(const v4i*)(_A1 + 512);  \
        A1[2] = *(const v4i*)(_A1 + 1024); A1[3] = *(const v4i*)(_A1 + 1536); \
        B1[0] = *(const v4i*)(_B1);        B1[1] = *(const v4i*)(_B1 + 512);  \
    } while (0)

#define MFMA16(A0, B0, A1, B1) do {                                           \
        __builtin_amdgcn_s_setprio(1);                                        \
        acc[0][0] = __builtin_amdgcn_mfma_i32_32x32x32_i8(A0[0], B0[0], acc[0][0], 0, 0, 0); \
        acc[0][1] = __builtin_amdgcn_mfma_i32_32x32x32_i8(A0[0], B0[1], acc[0][1], 0, 0, 0); \
        acc[1][0] = __builtin_amdgcn_mfma_i32_32x32x32_i8(A0[1], B0[0], acc[1][0], 0, 0, 0); \
        acc[1][1] = __builtin_amdgcn_mfma_i32_32x32x32_i8(A0[1], B0[1], acc[1][1], 0, 0, 0); \
        acc[2][0] = __builtin_amdgcn_mfma_i32_32x32x32_i8(A0[2], B0[0], acc[2][0], 0, 0, 0); \
        acc[2][1] = __builtin_amdgcn_mfma_i32_32x32x32_i8(A0[2], B0[1], acc[2][1], 0, 0, 0); \
        acc[3][0] = __builtin_amdgcn_mfma_i32_32x32x32_i8(A0[3], B0[0], acc[3][0], 0, 0, 0); \
        acc[3][1] = __builtin_amdgcn_mfma_i32_32x32x32_i8(A0[3], B0[1], acc[3][1], 0, 0, 0); \
        acc[0][0] = __builtin_amdgcn_mfma_i32_32x32x32_i8(A1[0], B1[0], acc[0][0], 0, 0, 0); \
        acc[0][1] = __builtin_amdgcn_mfma_i32_32x32x32_i8(A1[0], B1[1], acc[0][1], 0, 0, 0); \
        acc[1][0] = __builtin_amdgcn_mfma_i32_32x32x32_i8(A1[1], B1[0], acc[1][0], 0, 0, 0); \
        acc[1][1] = __builtin_amdgcn_mfma_i32_32x32x32_i8(A1[1], B1[1], acc[1][1], 0, 0, 0); \
        acc[2][0] = __builtin_amdgcn_mfma_i32_32x32x32_i8(A1[2], B1[0], acc[2][0], 0, 0, 0); \
        acc[2][1] = __builtin_amdgcn_mfma_i32_32x32x32_i8(A1[2], B1[1], acc[2][1], 0, 0, 0); \
        acc[3][0] = __builtin_amdgcn_mfma_i32_32x32x32_i8(A1[3], B1[0], acc[3][0], 0, 0, 0); \
        acc[3][1] = __builtin_amdgcn_mfma_i32_32x32x32_i8(A1[3], B1[1], acc[3][1], 0, 0, 0); \
        __builtin_amdgcn_s_setprio(0);                                        \
    } while (0)

    v16i acc[4][2];
#pragma unroll
    for (int mt = 0; mt < 4; ++mt)
#pragma unroll
        for (int nt = 0; nt < 2; ++nt)
#pragma unroll
            for (int r = 0; r < 16; ++r) acc[mt][nt][r] = 0;

    // two static fragment sets (rule #20: no runtime indexing)
    v4i f0A0[4], f0B0[2], f0A1[4], f0B1[2];   // even tiles
    v4i f1A0[4], f1B0[2], f1A1[4], f1B1[2];   // odd tiles

    // ---- prologue: 3 tiles in flight; tiles 0,1 resident; preload F0 ----
    stage(0); stage(1); stage(2);
    asm volatile("s_waitcnt vmcnt(4)" ::: "memory");   // tiles 0,1 done
    __builtin_amdgcn_s_barrier();
    READ12(f0A0, f0B0, f0A1, f0B1, 0);

    for (int j = 0; j < 15; ++j) {
        const int kt0 = 2 * j;
        // ---- tile kt0 (even, uses F0; prefetch F1 <- tile kt0+1) ----
        stage(kt0 + 3);
        READ12(f1A0, f1B0, f1A1, f1B1, kt0 + 1);
        MFMA16(f0A0, f0B0, f0A1, f0B1);
        asm volatile("s_waitcnt vmcnt(4)" ::: "memory");
        __builtin_amdgcn_s_barrier();
        // ---- tile kt0+1 (odd, uses F1; prefetch F0 <- tile kt0+2) ----
        stage(kt0 + 4);
        READ12(f0A0, f0B0, f0A1, f0B1, kt0 + 2);
        MFMA16(f1A0, f1B0, f1A1, f1B1);
        if (j < 14) asm volatile("s_waitcnt vmcnt(4)" ::: "memory");
        else        asm volatile("s_waitcnt vmcnt(0)" ::: "memory");
        __builtin_amdgcn_s_barrier();
    }
    // ---- tile 30 (uses F0; prefetch F1 <- tile 31; nothing left to stage) ----
    READ12(f1A0, f1B0, f1A1, f1B1, 31);
    MFMA16(f0A0, f0B0, f0A1, f0B1);
    // ---- tile 31 (uses F1) ----
    MFMA16(f1A0, f1B0, f1A1, f1B1);

    // ---- epilogue: out = fs*acc + mul*bias (nontemporal C-stream) ----
    // C/D layout (32x32): col = lane&31, row = (r&3) + 8*(r>>2) + 4*(lane>>5)
    const float fm = mulv[0];
    const float fs = fm * (__uint_as_float(scales[0]) / 128.0f)
                        * (__uint_as_float(scales[1]) / 127.0f);
    const int colb = bn * 256 + wc * 64 + ln;
    const int hi4  = hi * 4;
#pragma unroll
    for (int nt = 0; nt < 2; ++nt) {
        const int ocol = colb + nt * 32;
        const float bv = bias[ocol] * fm;
#pragma unroll
        for (int mt = 0; mt < 4; ++mt) {
            float* op = out + (size_t)(bm * 256 + wr * 128 + mt * 32) * NDIM + ocol;
#pragma unroll
            for (int r = 0; r < 16; ++r) {
                const int row = (r & 3) + 8 * (r >> 2) + hi4;
                __builtin_nontemporal_store(fs * (float)acc[mt][nt][r] + bv,
                                            op + (size_t)row * NDIM);
            }
        }
    }
#undef READ12
#undef MFMA16
}

extern "C" void kernel_launch(void* const* d_in, const int* in_sizes, int n_in,
                              void* d_out, int out_size, void* d_ws, size_t ws_size,
                              hipStream_t stream) {
    const float4* x    = (const float4*)d_in[0];
    const float4* wgt  = (const float4*)d_in[1];
    const float*  bias = (const float*)d_in[2];
    const float*  mulv = (const float*)d_in[3];
    float* out = (float*)d_out;

    // workspace: scales @0 (8B), partials @256 (12KB), qxp @16640, qwp next
    unsigned* scales  = (unsigned*)d_ws;
    float*    partial = (float*)((char*)d_ws + 256);
    signed char* qxp  = (signed char*)d_ws + 256 + 16384;
    signed char* qwp  = qxp + (size_t)MDIM * KDIM;

    absmax2<<<3072, 256, 0, stream>>>(x, wgt, partial);
    quant2<<<3072, 256, 0, stream>>>(x, (v4i*)qxp, wgt, (v4i*)qwp,
                                     partial, scales);
    gemm_i8<<<512, 512, 0, stream>>>(qxp, qwp, bias, mulv, scales, out);
}